// Round 8
// baseline (1989.231 us; speedup 1.0000x reference)
//
#include <hip/hip_runtime.h>

typedef _Float16 f16;
typedef _Float16 f16x8 __attribute__((ext_vector_type(8)));
typedef float f32x16 __attribute__((ext_vector_type(16)));

__device__ __forceinline__ f16x8 zero8() {
  f16x8 v;
#pragma unroll
  for (int j = 0; j < 8; ++j) v[j] = (f16)0.f;
  return v;
}

__device__ __forceinline__ f16x8 cvt8p(const float* p) {
  float4 a = *(const float4*)p;
  float4 b = *(const float4*)(p + 4);
  f16x8 v;
  v[0] = (f16)a.x; v[1] = (f16)a.y; v[2] = (f16)a.z; v[3] = (f16)a.w;
  v[4] = (f16)b.x; v[5] = (f16)b.y; v[6] = (f16)b.z; v[7] = (f16)b.w;
  return v;
}

__device__ __forceinline__ void gload16(const void* g, void* l) {
  __builtin_amdgcn_global_load_lds((const __attribute__((address_space(1))) unsigned int*)g,
                                   (__attribute__((address_space(3))) unsigned int*)l, 16, 0, 0);
}

__device__ __forceinline__ float sigm(float x) {
  return __builtin_amdgcn_rcpf(1.f + __expf(-x));
}
__device__ __forceinline__ float tanh_(float x) {
  x = fminf(15.f, fmaxf(-15.f, x));
  float e = __expf(2.f * x);
  return 1.f - 2.f * __builtin_amdgcn_rcpf(e + 1.f);
}

// ---------------- small utility kernels ----------------

__global__ void k_cvt8(const float* __restrict__ x, f16* __restrict__ y, long n) {
  long i = ((long)blockIdx.x * blockDim.x + threadIdx.x) * 8;
  long stride = (long)gridDim.x * blockDim.x * 8;
  for (; i < n; i += stride) *(f16x8*)(y + i) = cvt8p(x + i);
}

// k_gru weight image: [hb 8][kc 8][R 96][slot 8][8 f16]
// hb = hcol>>5; R = gate*32 + trow (trow = hcol&31). kc 0-3: Wc k=kc*64+kl;
// kc 4-7: Whh k=(kc-4)*64+kl. slot = (kl>>3) ^ (trow&7).
__global__ void k_wc2(const float* __restrict__ Wih, const float* __restrict__ W,
                      unsigned char* __restrict__ dstb) {
  int j = blockIdx.x;   // 0..767 = gate*256 + hcol
  int k = threadIdx.x;  // 0..255
  float s = 0.f;
  for (int c = 0; c < 256; ++c) s = fmaf(Wih[j * 256 + c], W[c * 256 + k], s);
  int g = j >> 8, hcol = j & 255;
  int hb = hcol >> 5, trow = hcol & 31;
  int kc = k >> 6, kl = k & 63;
  int slot = (kl >> 3) ^ (trow & 7);
  size_t byte = (size_t)hb * 98304 + (size_t)kc * 12288 +
                (size_t)(g * 32 + trow) * 128 + slot * 16 + (kl & 7) * 2;
  *(f16*)(dstb + byte) = (f16)s;
}

__global__ void k_whh2(const float* __restrict__ Whh, unsigned char* __restrict__ dstb) {
  int j = blockIdx.x;
  int k = threadIdx.x;
  float s = Whh[j * 256 + k];
  int g = j >> 8, hcol = j & 255;
  int hb = hcol >> 5, trow = hcol & 31;
  int kc = 4 + (k >> 6), kl = k & 63;
  int slot = (kl >> 3) ^ (trow & 7);
  size_t byte = (size_t)hb * 98304 + (size_t)kc * 12288 +
                (size_t)(g * 32 + trow) * 128 + slot * 16 + (kl & 7) * 2;
  *(f16*)(dstb + byte) = (f16)s;
}

// k_fn weight image: per chunk region of 69632B = 256 rows x 272B;
// kg at slot (kg + ((R>>3)&3)) & 15 (17th slot pad).
__global__ void k_prepw(const float* __restrict__ w, unsigned char* __restrict__ dstb) {
  int j = blockIdx.x;  // output col 0..255
  for (int k = threadIdx.x; k < 512; k += 256) {
    int chunk = k >> 7, kl = k & 127;
    int slot = ((kl >> 3) + ((j >> 3) & 3)) & 15;
    size_t byte = (size_t)chunk * 69632 + (size_t)j * 272 + slot * 16 + (kl & 7) * 2;
    *(f16*)(dstb + byte) = (f16)w[j * 512 + k];
  }
}

__global__ void k_v(const float* __restrict__ Wih, const float* __restrict__ b,
                    float* __restrict__ v) {
  int j = blockIdx.x * blockDim.x + threadIdx.x;
  if (j < 768) {
    float s = 0.f;
    for (int c = 0; c < 256; ++c) s = fmaf(Wih[j * 256 + c], b[c], s);
    v[j] = s;
  }
}

__global__ void k_hist(const int* __restrict__ dst, int* __restrict__ cnt, int E) {
  int e = blockIdx.x * 256 + threadIdx.x;
  if (e < E) atomicAdd(&cnt[dst[e]], 1);
}

__global__ void k_scan1(const int* __restrict__ deg, int* __restrict__ rowptr,
                        int* __restrict__ bsum, int n) {
  __shared__ int buf[256];
  int i = blockIdx.x * 256 + threadIdx.x;
  int v = (i < n) ? deg[i] : 0;
  buf[threadIdx.x] = v;
  __syncthreads();
  for (int off = 1; off < 256; off <<= 1) {
    int t = 0;
    if ((int)threadIdx.x >= off) t = buf[threadIdx.x - off];
    __syncthreads();
    buf[threadIdx.x] += t;
    __syncthreads();
  }
  if (i < n) rowptr[i] = buf[threadIdx.x] - v;
  if (threadIdx.x == 255) bsum[blockIdx.x] = buf[255];
}

__global__ void k_scan2(int* __restrict__ bsum, int nb) {
  __shared__ int buf[1024];
  int v = ((int)threadIdx.x < nb) ? bsum[threadIdx.x] : 0;
  buf[threadIdx.x] = v;
  __syncthreads();
  for (int off = 1; off < 1024; off <<= 1) {
    int t = 0;
    if ((int)threadIdx.x >= off) t = buf[threadIdx.x - off];
    __syncthreads();
    buf[threadIdx.x] += t;
    __syncthreads();
  }
  if ((int)threadIdx.x < nb) bsum[threadIdx.x] = buf[threadIdx.x] - v;
}

__global__ void k_scan3(int* __restrict__ rowptr, const int* __restrict__ bsum,
                        int n, int E) {
  int i = blockIdx.x * 256 + threadIdx.x;
  if (i < n) rowptr[i] += bsum[blockIdx.x];
  if (i == n) rowptr[n] = E;
}

__global__ void k_fill(const int* __restrict__ src, const int* __restrict__ dst,
                       const int* __restrict__ rowptr, int* __restrict__ cnt,
                       int* __restrict__ esrc, int E) {
  int e = blockIdx.x * 256 + threadIdx.x;
  if (e < E) {
    int d = dst[e];
    int r = atomicAdd(&cnt[d], 1);
    esrc[rowptr[d] + r] = src[e];
  }
}

__global__ void k_gather(const f16* __restrict__ h, const int* __restrict__ rowptr,
                         const int* __restrict__ esrc, f16* __restrict__ ag, int n) {
  int g = threadIdx.x >> 5, l = threadIdx.x & 31;
  int node = blockIdx.x * 8 + g;
  if (node >= n) return;
  int e0 = rowptr[node], e1 = rowptr[node + 1];
  float acc[8];
#pragma unroll
  for (int j = 0; j < 8; ++j) acc[j] = 0.f;
  for (int e = e0; e < e1; ++e) {
    int s = esrc[e];
    f16x8 hv = *(const f16x8*)(h + (long)s * 256 + l * 8);
#pragma unroll
    for (int j = 0; j < 8; ++j) acc[j] += (float)hv[j];
  }
  f16x8 o;
#pragma unroll
  for (int j = 0; j < 8; ++j) o[j] = (f16)acc[j];
  *(f16x8*)(ag + (long)node * 256 + l * 8) = o;
}

// ---------------- fused GRU kernel v8 ----------------
// Same math/image as v7 (verified), but K-chunked 12KB double-buffered staging:
// LDS = 2x12288 + Ds = 25.6KB -> 2-3 blocks/CU co-resident; cross-block wave
// overlap hides stage latency + barrier drains (v7 had 1 block/CU, fully exposed).
// Block = 256 rows x 32 hcols; 8 waves x 32 rows; wave-local GRU epilogue.
__global__ __launch_bounds__(512) void k_gru(
    const f16* __restrict__ ag, const f16* __restrict__ hin,
    const unsigned char* __restrict__ wprep, const float* __restrict__ bih,
    const float* __restrict__ bhh, const float* __restrict__ vv,
    const int* __restrict__ rowptr, f16* __restrict__ hout, int n, int nper) {
  __shared__ unsigned char SM[24576 + 1024];
  float* Ds = (float*)(SM + 24576);  // deg[256]
  int bid = blockIdx.x;
  int w = (bid & 7) * nper + (bid >> 3);  // XCD x gets w in [x*nper,(x+1)*nper)
  int rt = w >> 3, hb = w & 7;
  int row0 = rt * 256;
  int tid = threadIdx.x, lane = tid & 63, wid = tid >> 6;
  int l31 = lane & 31, hi = lane >> 5;
  const unsigned char* wb = wprep + (size_t)hb * 98304;

  auto stage = [&](int c, unsigned char* dst) {
    const unsigned char* s0 = wb + (size_t)c * 12288;
#pragma unroll
    for (int i = 0; i < 2; ++i) {
      int r = i * 8 + wid;
      if (r < 12) gload16(s0 + r * 1024 + lane * 16, dst + r * 1024);
    }
  };

  int arow = row0 + wid * 32 + l31;
  bool aok = arow < n;
  const f16* agp = ag + (size_t)arow * 256 + hi * 8;
  const f16* hp = hin + (size_t)arow * 256 + hi * 8;

  auto loadA = [&](f16x8(&dst)[4], const f16* p, int koff) {
#pragma unroll
    for (int ks = 0; ks < 4; ++ks)
      dst[ks] = aok ? *(const f16x8*)(p + koff + ks * 16) : zero8();
  };
  int sl0 = l31 & 7;
  auto runC = [&](const f16x8(&A)[4], const unsigned char* Bb, f32x16* accm) {
#pragma unroll
    for (int ks = 0; ks < 4; ++ks) {
      int sl = (ks * 2 + hi) ^ sl0;
#pragma unroll
      for (int g = 0; g < 3; ++g) {
        f16x8 b = *(const f16x8*)(Bb + (g * 32 + l31) * 128 + sl * 16);
        accm[g] = __builtin_amdgcn_mfma_f32_32x32x16_f16(A[ks], b, accm[g], 0, 0, 0);
      }
    }
  };

  f32x16 acc[6];  // 0-2: gi (r,z,n), 3-5: gh
#pragma unroll
  for (int t = 0; t < 6; ++t)
#pragma unroll
    for (int j = 0; j < 16; ++j) acc[t][j] = 0.f;

  f16x8 a0[4], a1[4];

  // prologue: chunk 0 + deg
  stage(0, SM);
  loadA(a0, agp, 0);
  if (tid < 256) {
    int grow = row0 + tid;
    Ds[tid] = (grow < n) ? (float)(rowptr[grow + 1] - rowptr[grow]) : 0.f;
  }
  __syncthreads();

  stage(1, SM + 12288); loadA(a1, agp, 64);
  runC(a0, SM, acc);            // c0 (gi)
  __syncthreads();
  stage(2, SM);         loadA(a0, agp, 128);
  runC(a1, SM + 12288, acc);    // c1
  __syncthreads();
  stage(3, SM + 12288); loadA(a1, agp, 192);
  runC(a0, SM, acc);            // c2
  __syncthreads();
  stage(4, SM);         loadA(a0, hp, 0);
  runC(a1, SM + 12288, acc);    // c3
  __syncthreads();
  stage(5, SM + 12288); loadA(a1, hp, 64);
  runC(a0, SM, acc + 3);        // c4 (gh)
  __syncthreads();
  stage(6, SM);         loadA(a0, hp, 128);
  runC(a1, SM + 12288, acc + 3);  // c5
  __syncthreads();
  stage(7, SM + 12288); loadA(a1, hp, 192);
  runC(a0, SM, acc + 3);        // c6
  __syncthreads();
  runC(a1, SM + 12288, acc + 3);  // c7

  // wave-local GRU epilogue. C layout: col = l31 (hcol), row = crow(rg,hi).
  int gcol = hb * 32 + l31;
  float br = bih[gcol] + bhh[gcol];
  float bz = bih[256 + gcol] + bhh[256 + gcol];
  float bi_n = bih[512 + gcol], bh_n = bhh[512 + gcol];
  float vr = vv[gcol], vz = vv[256 + gcol], vn = vv[512 + gcol];
  int wrow = wid * 32;

  float hold[16];
#pragma unroll
  for (int rg = 0; rg < 16; ++rg) {
    int grow = row0 + wrow + (rg & 3) + 8 * (rg >> 2) + 4 * hi;
    hold[rg] = (grow < n) ? (float)hin[(size_t)grow * 256 + gcol] : 0.f;
  }
#pragma unroll
  for (int rg = 0; rg < 16; ++rg) {
    int crow = (rg & 3) + 8 * (rg >> 2) + 4 * hi;
    int grow = row0 + wrow + crow;
    float dg = Ds[wrow + crow];
    float r = sigm(acc[0][rg] + acc[3][rg] + br + dg * vr);
    float z = sigm(acc[1][rg] + acc[4][rg] + bz + dg * vz);
    float nn = tanh_(acc[2][rg] + bi_n + dg * vn + r * (acc[5][rg] + bh_n));
    if (grow < n)
      hout[(size_t)grow * 256 + gcol] = (f16)((1.f - z) * nn + z * hold[rg]);
  }
}

// ---------------- fused concat-linear (unchanged): out = [hb | base] @ w^T + bias
__global__ __launch_bounds__(512, 2) void k_fn(
    const f16* __restrict__ hb, const float* __restrict__ base,
    const unsigned char* __restrict__ wp, const float* __restrict__ bias,
    float* __restrict__ out, int n) {
  __shared__ unsigned char SM[69632];
  int row0 = blockIdx.x * 128;
  int tid = threadIdx.x, lane = tid & 63, wid = tid >> 6;
  int l31 = lane & 31, hi = lane >> 5;
  int rs = wid >> 2, cgf = wid & 3;
  int arow[2];
  arow[0] = row0 + rs * 64 + l31;
  arow[1] = arow[0] + 32;
  int srot = (l31 >> 3) & 3;

  f32x16 acc[2][2];  // [rowgrp][tile]
#pragma unroll
  for (int q = 0; q < 2; ++q)
#pragma unroll
    for (int t = 0; t < 2; ++t)
#pragma unroll
      for (int j = 0; j < 16; ++j) acc[q][t][j] = 0.f;

#pragma unroll
  for (int c = 0; c < 4; ++c) {
    if (c) __syncthreads();
    for (int i = wid; i < 68; i += 8)
      gload16(wp + (size_t)c * 69632 + i * 1024 + lane * 16, SM + i * 1024);
    f16x8 areg[2][8];
#pragma unroll
    for (int q = 0; q < 2; ++q) {
      bool ok = arow[q] < n;
#pragma unroll
      for (int ks = 0; ks < 8; ++ks) {
        int k = c * 128 + ks * 16 + hi * 8;
        if (!ok)
          areg[q][ks] = zero8();
        else if (k < 256)
          areg[q][ks] = *(const f16x8*)(hb + (size_t)arow[q] * 256 + k);
        else
          areg[q][ks] = cvt8p(base + (size_t)arow[q] * 256 + (k - 256));
      }
    }
    __syncthreads();
#pragma unroll
    for (int ks = 0; ks < 8; ++ks) {
      int slot = ((ks * 2 + hi) + srot) & 15;
#pragma unroll
      for (int t = 0; t < 2; ++t) {
        int R = cgf * 64 + t * 32 + l31;
        f16x8 b = *(const f16x8*)(SM + R * 272 + slot * 16);
        acc[0][t] = __builtin_amdgcn_mfma_f32_32x32x16_f16(areg[0][ks], b, acc[0][t], 0, 0, 0);
        acc[1][t] = __builtin_amdgcn_mfma_f32_32x32x16_f16(areg[1][ks], b, acc[1][t], 0, 0, 0);
      }
    }
  }

#pragma unroll
  for (int t = 0; t < 2; ++t) {
    int col = cgf * 64 + t * 32 + l31;
    float bb = bias[col];
#pragma unroll
    for (int q = 0; q < 2; ++q) {
#pragma unroll
      for (int rg = 0; rg < 16; ++rg) {
        int grow = row0 + rs * 64 + q * 32 + (rg & 3) + 8 * (rg >> 2) + 4 * hi;
        if (grow < n) out[(size_t)grow * 256 + col] = acc[q][t][rg] + bb;
      }
    }
  }
}

// ---------------- launch ----------------
extern "C" void kernel_launch(void* const* d_in, const int* in_sizes, int n_in,
                              void* d_out, int out_size, void* d_ws, size_t ws_size,
                              hipStream_t stream) {
  const float* nodes = (const float*)d_in[0];
  const int* asrc = (const int*)d_in[1];
  const int* adst = (const int*)d_in[2];
  const int* csrc = (const int*)d_in[3];
  const int* cdst = (const int*)d_in[4];
  const float* W_ast = (const float*)d_in[5];
  const float* b_ast = (const float*)d_in[6];
  const float* Wih_a = (const float*)d_in[7];
  const float* Whh_a = (const float*)d_in[8];
  const float* bih_a = (const float*)d_in[9];
  const float* bhh_a = (const float*)d_in[10];
  const float* w1 = (const float*)d_in[11];
  const float* b1 = (const float*)d_in[12];
  const float* W_cpg = (const float*)d_in[13];
  const float* b_cpg = (const float*)d_in[14];
  const float* Wih_c = (const float*)d_in[15];
  const float* Whh_c = (const float*)d_in[16];
  const float* bih_c = (const float*)d_in[17];
  const float* bhh_c = (const float*)d_in[18];
  const float* w2 = (const float*)d_in[19];
  const float* b2 = (const float*)d_in[20];
  float* out = (float*)d_out;

  const int N = in_sizes[0] / 256;  // 150000
  const int EA = in_sizes[1];       // 300000
  const int EC = in_sizes[3];       // 250000
  const long ND = (long)N * 256;

  char* ws = (char*)d_ws;
  size_t off = 0;
  auto carve = [&](size_t bytes) -> char* {
    char* p = ws + off;
    off += (bytes + 255) & ~(size_t)255;
    return p;
  };
  f16* h0 = (f16*)carve(ND * 2);
  f16* h1 = (f16*)carve(ND * 2);
  f16* ag = (f16*)carve(ND * 2);
  unsigned char* wpA = (unsigned char*)carve(786432);  // 8 hb x 8 kc x 12288B
  unsigned char* wpC = (unsigned char*)carve(786432);
  unsigned char* w1p = (unsigned char*)carve(278528);  // 4 chunks x 69632B
  unsigned char* w2p = (unsigned char*)carve(278528);
  float* vA = (float*)carve(768 * 4);
  float* vC = (float*)carve(768 * 4);
  int* rowptr = (int*)carve((size_t)(N + 1) * 4);
  int* cnt = (int*)carve((size_t)N * 4);
  int* esrc = (int*)carve((size_t)(EA > EC ? EA : EC) * 4);
  int* bsum = (int*)carve(1024 * 4);
  (void)ws_size; (void)n_in; (void)out_size;

  const int NRB = (N + 255) / 256;   // 586 row-panels
  const int FBLK = (N + 127) / 128;  // 1172 for k_fn
  const int SBLK = (N + 255) / 256;  // 586 for scans
  auto cvt = [&](const float* x, f16* y, long n) {
    int blocks = (int)((n / 8 + 255) / 256);
    if (blocks > 2048) blocks = 2048;
    k_cvt8<<<blocks, 256, 0, stream>>>(x, y, n);
  };

  // weight prep (conflict-free LDS images)
  k_wc2<<<768, 256, 0, stream>>>(Wih_a, W_ast, wpA);
  k_wc2<<<768, 256, 0, stream>>>(Wih_c, W_cpg, wpC);
  k_whh2<<<768, 256, 0, stream>>>(Whh_a, wpA);
  k_whh2<<<768, 256, 0, stream>>>(Whh_c, wpC);
  k_prepw<<<256, 256, 0, stream>>>(w1, w1p);
  k_prepw<<<256, 256, 0, stream>>>(w2, w2p);
  k_v<<<3, 256, 0, stream>>>(Wih_a, b_ast, vA);
  k_v<<<3, 256, 0, stream>>>(Wih_c, b_cpg, vC);
  cvt(nodes, h0, ND);

  auto run_branch = [&](const int* src, const int* dst, int E, const unsigned char* wprep,
                        const float* bih, const float* bhh, const float* v) {
    hipMemsetAsync(cnt, 0, (size_t)N * 4, stream);
    k_hist<<<(E + 255) / 256, 256, 0, stream>>>(dst, cnt, E);
    k_scan1<<<SBLK, 256, 0, stream>>>(cnt, rowptr, bsum, N);
    k_scan2<<<1, 1024, 0, stream>>>(bsum, SBLK);
    k_scan3<<<SBLK, 256, 0, stream>>>(rowptr, bsum, N, E);
    hipMemsetAsync(cnt, 0, (size_t)N * 4, stream);
    k_fill<<<(E + 255) / 256, 256, 0, stream>>>(src, dst, rowptr, cnt, esrc, E);
    k_gather<<<(N + 7) / 8, 256, 0, stream>>>(h0, rowptr, esrc, ag, N);
    k_gru<<<NRB * 8, 512, 0, stream>>>(ag, h0, wprep, bih, bhh, v, rowptr, h1, N, NRB);
    k_gather<<<(N + 7) / 8, 256, 0, stream>>>(h1, rowptr, esrc, ag, N);
    k_gru<<<NRB * 8, 512, 0, stream>>>(ag, h1, wprep, bih, bhh, v, rowptr, h0, N, NRB);
  };

  run_branch(asrc, adst, EA, wpA, bih_a, bhh_a, vA);
  k_fn<<<FBLK, 512, 0, stream>>>(h0, nodes, w1p, b1, out, N);
  cvt(out, h0, ND);
  run_branch(csrc, cdst, EC, wpC, bih_c, bhh_c, vC);
  k_fn<<<FBLK, 512, 0, stream>>>(h0, out, w2p, b2, out, N);
}

// Round 9
// 1557.930 us; speedup vs baseline: 1.2768x; 1.2768x over previous
//
#include <hip/hip_runtime.h>

typedef _Float16 f16;
typedef _Float16 f16x8 __attribute__((ext_vector_type(8)));
typedef float f32x16 __attribute__((ext_vector_type(16)));

__device__ __forceinline__ f16x8 zero8() {
  f16x8 v;
#pragma unroll
  for (int j = 0; j < 8; ++j) v[j] = (f16)0.f;
  return v;
}

__device__ __forceinline__ f16x8 cvt8p(const float* p) {
  float4 a = *(const float4*)p;
  float4 b = *(const float4*)(p + 4);
  f16x8 v;
  v[0] = (f16)a.x; v[1] = (f16)a.y; v[2] = (f16)a.z; v[3] = (f16)a.w;
  v[4] = (f16)b.x; v[5] = (f16)b.y; v[6] = (f16)b.z; v[7] = (f16)b.w;
  return v;
}

__device__ __forceinline__ void gload16(const void* g, void* l) {
  __builtin_amdgcn_global_load_lds((const __attribute__((address_space(1))) unsigned int*)g,
                                   (__attribute__((address_space(3))) unsigned int*)l, 16, 0, 0);
}

__device__ __forceinline__ float sigm(float x) {
  return __builtin_amdgcn_rcpf(1.f + __expf(-x));
}
__device__ __forceinline__ float tanh_(float x) {
  x = fminf(15.f, fmaxf(-15.f, x));
  float e = __expf(2.f * x);
  return 1.f - 2.f * __builtin_amdgcn_rcpf(e + 1.f);
}

// ---------------- small utility kernels ----------------

__global__ void k_cvt8(const float* __restrict__ x, f16* __restrict__ y, long n) {
  long i = ((long)blockIdx.x * blockDim.x + threadIdx.x) * 8;
  long stride = (long)gridDim.x * blockDim.x * 8;
  for (; i < n; i += stride) *(f16x8*)(y + i) = cvt8p(x + i);
}

// k_gru weight image: [hb 8][kc 8][R 96][slot 8][8 f16]
// hb = hcol>>5; R = gate*32 + trow (trow = hcol&31). kc 0-3: Wc k=kc*64+kl;
// kc 4-7: Whh k=(kc-4)*64+kl. slot = (kl>>3) ^ (trow&7).
__global__ void k_wc2(const float* __restrict__ Wih, const float* __restrict__ W,
                      unsigned char* __restrict__ dstb) {
  int j = blockIdx.x;   // 0..767 = gate*256 + hcol
  int k = threadIdx.x;  // 0..255
  float s = 0.f;
  for (int c = 0; c < 256; ++c) s = fmaf(Wih[j * 256 + c], W[c * 256 + k], s);
  int g = j >> 8, hcol = j & 255;
  int hb = hcol >> 5, trow = hcol & 31;
  int kc = k >> 6, kl = k & 63;
  int slot = (kl >> 3) ^ (trow & 7);
  size_t byte = (size_t)hb * 98304 + (size_t)kc * 12288 +
                (size_t)(g * 32 + trow) * 128 + slot * 16 + (kl & 7) * 2;
  *(f16*)(dstb + byte) = (f16)s;
}

__global__ void k_whh2(const float* __restrict__ Whh, unsigned char* __restrict__ dstb) {
  int j = blockIdx.x;
  int k = threadIdx.x;
  float s = Whh[j * 256 + k];
  int g = j >> 8, hcol = j & 255;
  int hb = hcol >> 5, trow = hcol & 31;
  int kc = 4 + (k >> 6), kl = k & 63;
  int slot = (kl >> 3) ^ (trow & 7);
  size_t byte = (size_t)hb * 98304 + (size_t)kc * 12288 +
                (size_t)(g * 32 + trow) * 128 + slot * 16 + (kl & 7) * 2;
  *(f16*)(dstb + byte) = (f16)s;
}

// k_fn weight image: per chunk region of 69632B = 256 rows x 272B;
// kg at slot (kg + ((R>>3)&3)) & 15 (17th slot pad).
__global__ void k_prepw(const float* __restrict__ w, unsigned char* __restrict__ dstb) {
  int j = blockIdx.x;  // output col 0..255
  for (int k = threadIdx.x; k < 512; k += 256) {
    int chunk = k >> 7, kl = k & 127;
    int slot = ((kl >> 3) + ((j >> 3) & 3)) & 15;
    size_t byte = (size_t)chunk * 69632 + (size_t)j * 272 + slot * 16 + (kl & 7) * 2;
    *(f16*)(dstb + byte) = (f16)w[j * 512 + k];
  }
}

__global__ void k_v(const float* __restrict__ Wih, const float* __restrict__ b,
                    float* __restrict__ v) {
  int j = blockIdx.x * blockDim.x + threadIdx.x;
  if (j < 768) {
    float s = 0.f;
    for (int c = 0; c < 256; ++c) s = fmaf(Wih[j * 256 + c], b[c], s);
    v[j] = s;
  }
}

__global__ void k_hist(const int* __restrict__ dst, int* __restrict__ cnt, int E) {
  int e = blockIdx.x * 256 + threadIdx.x;
  if (e < E) atomicAdd(&cnt[dst[e]], 1);
}

__global__ void k_scan1(const int* __restrict__ deg, int* __restrict__ rowptr,
                        int* __restrict__ bsum, int n) {
  __shared__ int buf[256];
  int i = blockIdx.x * 256 + threadIdx.x;
  int v = (i < n) ? deg[i] : 0;
  buf[threadIdx.x] = v;
  __syncthreads();
  for (int off = 1; off < 256; off <<= 1) {
    int t = 0;
    if ((int)threadIdx.x >= off) t = buf[threadIdx.x - off];
    __syncthreads();
    buf[threadIdx.x] += t;
    __syncthreads();
  }
  if (i < n) rowptr[i] = buf[threadIdx.x] - v;
  if (threadIdx.x == 255) bsum[blockIdx.x] = buf[255];
}

__global__ void k_scan2(int* __restrict__ bsum, int nb) {
  __shared__ int buf[1024];
  int v = ((int)threadIdx.x < nb) ? bsum[threadIdx.x] : 0;
  buf[threadIdx.x] = v;
  __syncthreads();
  for (int off = 1; off < 1024; off <<= 1) {
    int t = 0;
    if ((int)threadIdx.x >= off) t = buf[threadIdx.x - off];
    __syncthreads();
    buf[threadIdx.x] += t;
    __syncthreads();
  }
  if ((int)threadIdx.x < nb) bsum[threadIdx.x] = buf[threadIdx.x] - v;
}

__global__ void k_scan3(int* __restrict__ rowptr, const int* __restrict__ bsum,
                        int n, int E) {
  int i = blockIdx.x * 256 + threadIdx.x;
  if (i < n) rowptr[i] += bsum[blockIdx.x];
  if (i == n) rowptr[n] = E;
}

__global__ void k_fill(const int* __restrict__ src, const int* __restrict__ dst,
                       const int* __restrict__ rowptr, int* __restrict__ cnt,
                       int* __restrict__ esrc, int E) {
  int e = blockIdx.x * 256 + threadIdx.x;
  if (e < E) {
    int d = dst[e];
    int r = atomicAdd(&cnt[d], 1);
    esrc[rowptr[d] + r] = src[e];
  }
}

__global__ void k_gather(const f16* __restrict__ h, const int* __restrict__ rowptr,
                         const int* __restrict__ esrc, f16* __restrict__ ag, int n) {
  int g = threadIdx.x >> 5, l = threadIdx.x & 31;
  int node = blockIdx.x * 8 + g;
  if (node >= n) return;
  int e0 = rowptr[node], e1 = rowptr[node + 1];
  float acc[8];
#pragma unroll
  for (int j = 0; j < 8; ++j) acc[j] = 0.f;
  for (int e = e0; e < e1; ++e) {
    int s = esrc[e];
    f16x8 hv = *(const f16x8*)(h + (long)s * 256 + l * 8);
#pragma unroll
    for (int j = 0; j < 8; ++j) acc[j] += (float)hv[j];
  }
  f16x8 o;
#pragma unroll
  for (int j = 0; j < 8; ++j) o[j] = (f16)acc[j];
  *(f16x8*)(ag + (long)node * 256 + l * 8) = o;
}

// ---------------- fused GRU kernel v9 ----------------
// Occupancy-first: 256 thr / 4 waves, wave = 32 rows x 32 hcols x 3 gates,
// acc = 4 tiles (64 AGPR; r,z shared across gi/gh halves, n split), single
// A buffer, launch_bounds(256,4) -> 128 unified regs -> 16 waves/CU (4 blocks).
// Same verified weight image / swizzle / XCD map / epilogue math as v7/v8.
__global__ __launch_bounds__(256, 4) void k_gru(
    const f16* __restrict__ ag, const f16* __restrict__ hin,
    const unsigned char* __restrict__ wprep, const float* __restrict__ bih,
    const float* __restrict__ bhh, const float* __restrict__ vv,
    const int* __restrict__ rowptr, f16* __restrict__ hout, int n, int nper) {
  __shared__ unsigned char SM[24576 + 512];
  float* Ds = (float*)(SM + 24576);  // deg[128]
  int bid = blockIdx.x;
  int w = (bid & 7) * nper + (bid >> 3);  // XCD x gets w in [x*nper,(x+1)*nper)
  int rt = w >> 3, hb = w & 7;
  int row0 = rt * 128;
  int tid = threadIdx.x, lane = tid & 63, wid = tid >> 6;  // 4 waves
  int l31 = lane & 31, hi = lane >> 5;
  const unsigned char* wb = wprep + (size_t)hb * 98304;

  auto stage = [&](int c, unsigned char* dst) {
    const unsigned char* s0 = wb + (size_t)c * 12288;
#pragma unroll
    for (int i = 0; i < 3; ++i) {
      int r = i * 4 + wid;
      gload16(s0 + r * 1024 + lane * 16, dst + r * 1024);
    }
  };

  int arow = row0 + wid * 32 + l31;
  bool aok = arow < n;
  const f16* agp = ag + (size_t)arow * 256 + hi * 8;
  const f16* hp = hin + (size_t)arow * 256 + hi * 8;

  f16x8 a[4];
  auto loadA = [&](const f16* p, int koff) {
#pragma unroll
    for (int ks = 0; ks < 4; ++ks)
      a[ks] = aok ? *(const f16x8*)(p + koff + ks * 16) : zero8();
  };
  int sl0 = l31 & 7;
  auto runC = [&](const unsigned char* Bb, f32x16& aR, f32x16& aZ, f32x16& aN) {
#pragma unroll
    for (int ks = 0; ks < 4; ++ks) {
      int sl = (ks * 2 + hi) ^ sl0;
      const unsigned char* base = Bb + sl * 16;
      f16x8 b0 = *(const f16x8*)(base + (0 * 32 + l31) * 128);
      aR = __builtin_amdgcn_mfma_f32_32x32x16_f16(a[ks], b0, aR, 0, 0, 0);
      f16x8 b1 = *(const f16x8*)(base + (1 * 32 + l31) * 128);
      aZ = __builtin_amdgcn_mfma_f32_32x32x16_f16(a[ks], b1, aZ, 0, 0, 0);
      f16x8 b2 = *(const f16x8*)(base + (2 * 32 + l31) * 128);
      aN = __builtin_amdgcn_mfma_f32_32x32x16_f16(a[ks], b2, aN, 0, 0, 0);
    }
  };

  f32x16 accR, accZ, accNI, accNH;
#pragma unroll
  for (int j = 0; j < 16; ++j) { accR[j] = 0.f; accZ[j] = 0.f; accNI[j] = 0.f; accNH[j] = 0.f; }

  // prologue: chunk 0 + deg
  stage(0, SM);
  loadA(agp, 0);
  if (tid < 128) {
    int grow = row0 + tid;
    Ds[tid] = (grow < n) ? (float)(rowptr[grow + 1] - rowptr[grow]) : 0.f;
  }
  __syncthreads();

  // chunks 0-3: gi half (A = ag, B = Wc)
  stage(1, SM + 12288);
  runC(SM, accR, accZ, accNI);
  loadA(agp, 64);
  __syncthreads();
  stage(2, SM);
  runC(SM + 12288, accR, accZ, accNI);
  loadA(agp, 128);
  __syncthreads();
  stage(3, SM + 12288);
  runC(SM, accR, accZ, accNI);
  loadA(agp, 192);
  __syncthreads();
  stage(4, SM);
  runC(SM + 12288, accR, accZ, accNI);
  loadA(hp, 0);
  __syncthreads();
  // chunks 4-7: gh half (A = hin, B = Whh); r/z accumulate into SAME tiles
  stage(5, SM + 12288);
  runC(SM, accR, accZ, accNH);
  loadA(hp, 64);
  __syncthreads();
  stage(6, SM);
  runC(SM + 12288, accR, accZ, accNH);
  loadA(hp, 128);
  __syncthreads();
  stage(7, SM + 12288);
  runC(SM, accR, accZ, accNH);
  loadA(hp, 192);
  __syncthreads();
  runC(SM + 12288, accR, accZ, accNH);

  // wave-local GRU epilogue. C layout: col = l31 (hcol), row = crow(rg,hi).
  int gcol = hb * 32 + l31;
  float br = bih[gcol] + bhh[gcol];
  float bz = bih[256 + gcol] + bhh[256 + gcol];
  float bi_n = bih[512 + gcol], bh_n = bhh[512 + gcol];
  float vr = vv[gcol], vz = vv[256 + gcol], vn = vv[512 + gcol];
  int wrow = wid * 32;

#pragma unroll
  for (int rg = 0; rg < 16; ++rg) {
    int crow = (rg & 3) + 8 * (rg >> 2) + 4 * hi;
    int grow = row0 + wrow + crow;
    float dg = Ds[wrow + crow];
    float hold = (grow < n) ? (float)hin[(size_t)grow * 256 + gcol] : 0.f;
    float r = sigm(accR[rg] + br + dg * vr);
    float z = sigm(accZ[rg] + bz + dg * vz);
    float nn = tanh_(accNI[rg] + bi_n + dg * vn + r * (accNH[rg] + bh_n));
    if (grow < n)
      hout[(size_t)grow * 256 + gcol] = (f16)((1.f - z) * nn + z * hold);
  }
}

// ---------------- fused concat-linear (unchanged): out = [hb | base] @ w^T + bias
__global__ __launch_bounds__(512, 2) void k_fn(
    const f16* __restrict__ hb, const float* __restrict__ base,
    const unsigned char* __restrict__ wp, const float* __restrict__ bias,
    float* __restrict__ out, int n) {
  __shared__ unsigned char SM[69632];
  int row0 = blockIdx.x * 128;
  int tid = threadIdx.x, lane = tid & 63, wid = tid >> 6;
  int l31 = lane & 31, hi = lane >> 5;
  int rs = wid >> 2, cgf = wid & 3;
  int arow[2];
  arow[0] = row0 + rs * 64 + l31;
  arow[1] = arow[0] + 32;
  int srot = (l31 >> 3) & 3;

  f32x16 acc[2][2];  // [rowgrp][tile]
#pragma unroll
  for (int q = 0; q < 2; ++q)
#pragma unroll
    for (int t = 0; t < 2; ++t)
#pragma unroll
      for (int j = 0; j < 16; ++j) acc[q][t][j] = 0.f;

#pragma unroll
  for (int c = 0; c < 4; ++c) {
    if (c) __syncthreads();
    for (int i = wid; i < 68; i += 8)
      gload16(wp + (size_t)c * 69632 + i * 1024 + lane * 16, SM + i * 1024);
    f16x8 areg[2][8];
#pragma unroll
    for (int q = 0; q < 2; ++q) {
      bool ok = arow[q] < n;
#pragma unroll
      for (int ks = 0; ks < 8; ++ks) {
        int k = c * 128 + ks * 16 + hi * 8;
        if (!ok)
          areg[q][ks] = zero8();
        else if (k < 256)
          areg[q][ks] = *(const f16x8*)(hb + (size_t)arow[q] * 256 + k);
        else
          areg[q][ks] = cvt8p(base + (size_t)arow[q] * 256 + (k - 256));
      }
    }
    __syncthreads();
#pragma unroll
    for (int ks = 0; ks < 8; ++ks) {
      int slot = ((ks * 2 + hi) + srot) & 15;
#pragma unroll
      for (int t = 0; t < 2; ++t) {
        int R = cgf * 64 + t * 32 + l31;
        f16x8 b = *(const f16x8*)(SM + R * 272 + slot * 16);
        acc[0][t] = __builtin_amdgcn_mfma_f32_32x32x16_f16(areg[0][ks], b, acc[0][t], 0, 0, 0);
        acc[1][t] = __builtin_amdgcn_mfma_f32_32x32x16_f16(areg[1][ks], b, acc[1][t], 0, 0, 0);
      }
    }
  }

#pragma unroll
  for (int t = 0; t < 2; ++t) {
    int col = cgf * 64 + t * 32 + l31;
    float bb = bias[col];
#pragma unroll
    for (int q = 0; q < 2; ++q) {
#pragma unroll
      for (int rg = 0; rg < 16; ++rg) {
        int grow = row0 + rs * 64 + q * 32 + (rg & 3) + 8 * (rg >> 2) + 4 * hi;
        if (grow < n) out[(size_t)grow * 256 + col] = acc[q][t][rg] + bb;
      }
    }
  }
}

// ---------------- launch ----------------
extern "C" void kernel_launch(void* const* d_in, const int* in_sizes, int n_in,
                              void* d_out, int out_size, void* d_ws, size_t ws_size,
                              hipStream_t stream) {
  const float* nodes = (const float*)d_in[0];
  const int* asrc = (const int*)d_in[1];
  const int* adst = (const int*)d_in[2];
  const int* csrc = (const int*)d_in[3];
  const int* cdst = (const int*)d_in[4];
  const float* W_ast = (const float*)d_in[5];
  const float* b_ast = (const float*)d_in[6];
  const float* Wih_a = (const float*)d_in[7];
  const float* Whh_a = (const float*)d_in[8];
  const float* bih_a = (const float*)d_in[9];
  const float* bhh_a = (const float*)d_in[10];
  const float* w1 = (const float*)d_in[11];
  const float* b1 = (const float*)d_in[12];
  const float* W_cpg = (const float*)d_in[13];
  const float* b_cpg = (const float*)d_in[14];
  const float* Wih_c = (const float*)d_in[15];
  const float* Whh_c = (const float*)d_in[16];
  const float* bih_c = (const float*)d_in[17];
  const float* bhh_c = (const float*)d_in[18];
  const float* w2 = (const float*)d_in[19];
  const float* b2 = (const float*)d_in[20];
  float* out = (float*)d_out;

  const int N = in_sizes[0] / 256;  // 150000
  const int EA = in_sizes[1];       // 300000
  const int EC = in_sizes[3];       // 250000
  const long ND = (long)N * 256;

  char* ws = (char*)d_ws;
  size_t off = 0;
  auto carve = [&](size_t bytes) -> char* {
    char* p = ws + off;
    off += (bytes + 255) & ~(size_t)255;
    return p;
  };
  f16* h0 = (f16*)carve(ND * 2);
  f16* h1 = (f16*)carve(ND * 2);
  f16* ag = (f16*)carve(ND * 2);
  unsigned char* wpA = (unsigned char*)carve(786432);  // 8 hb x 8 kc x 12288B
  unsigned char* wpC = (unsigned char*)carve(786432);
  unsigned char* w1p = (unsigned char*)carve(278528);  // 4 chunks x 69632B
  unsigned char* w2p = (unsigned char*)carve(278528);
  float* vA = (float*)carve(768 * 4);
  float* vC = (float*)carve(768 * 4);
  int* rowptr = (int*)carve((size_t)(N + 1) * 4);
  int* cnt = (int*)carve((size_t)N * 4);
  int* esrc = (int*)carve((size_t)(EA > EC ? EA : EC) * 4);
  int* bsum = (int*)carve(1024 * 4);
  (void)ws_size; (void)n_in; (void)out_size;

  const int NRB = (N + 127) / 128;   // 1172 row-panels (128 rows each)
  const int FBLK = (N + 127) / 128;  // 1172 for k_fn
  const int SBLK = (N + 255) / 256;  // 586 for scans
  auto cvt = [&](const float* x, f16* y, long n) {
    int blocks = (int)((n / 8 + 255) / 256);
    if (blocks > 2048) blocks = 2048;
    k_cvt8<<<blocks, 256, 0, stream>>>(x, y, n);
  };

  // weight prep (conflict-free LDS images)
  k_wc2<<<768, 256, 0, stream>>>(Wih_a, W_ast, wpA);
  k_wc2<<<768, 256, 0, stream>>>(Wih_c, W_cpg, wpC);
  k_whh2<<<768, 256, 0, stream>>>(Whh_a, wpA);
  k_whh2<<<768, 256, 0, stream>>>(Whh_c, wpC);
  k_prepw<<<256, 256, 0, stream>>>(w1, w1p);
  k_prepw<<<256, 256, 0, stream>>>(w2, w2p);
  k_v<<<3, 256, 0, stream>>>(Wih_a, b_ast, vA);
  k_v<<<3, 256, 0, stream>>>(Wih_c, b_cpg, vC);
  cvt(nodes, h0, ND);

  auto run_branch = [&](const int* src, const int* dst, int E, const unsigned char* wprep,
                        const float* bih, const float* bhh, const float* v) {
    hipMemsetAsync(cnt, 0, (size_t)N * 4, stream);
    k_hist<<<(E + 255) / 256, 256, 0, stream>>>(dst, cnt, E);
    k_scan1<<<SBLK, 256, 0, stream>>>(cnt, rowptr, bsum, N);
    k_scan2<<<1, 1024, 0, stream>>>(bsum, SBLK);
    k_scan3<<<SBLK, 256, 0, stream>>>(rowptr, bsum, N, E);
    hipMemsetAsync(cnt, 0, (size_t)N * 4, stream);
    k_fill<<<(E + 255) / 256, 256, 0, stream>>>(src, dst, rowptr, cnt, esrc, E);
    k_gather<<<(N + 7) / 8, 256, 0, stream>>>(h0, rowptr, esrc, ag, N);
    k_gru<<<NRB * 8, 256, 0, stream>>>(ag, h0, wprep, bih, bhh, v, rowptr, h1, N, NRB);
    k_gather<<<(N + 7) / 8, 256, 0, stream>>>(h1, rowptr, esrc, ag, N);
    k_gru<<<NRB * 8, 256, 0, stream>>>(ag, h1, wprep, bih, bhh, v, rowptr, h0, N, NRB);
  };

  run_branch(asrc, adst, EA, wpA, bih_a, bhh_a, vA);
  k_fn<<<FBLK, 512, 0, stream>>>(h0, nodes, w1p, b1, out, N);
  cvt(out, h0, ND);
  run_branch(csrc, cdst, EC, wpC, bih_c, bhh_c, vC);
  k_fn<<<FBLK, 512, 0, stream>>>(h0, out, w2p, b2, out, N);
}

// Round 12
// 1384.261 us; speedup vs baseline: 1.4370x; 1.1255x over previous
//
#include <hip/hip_runtime.h>

typedef _Float16 f16;
typedef _Float16 f16x8 __attribute__((ext_vector_type(8)));
typedef float f32x16 __attribute__((ext_vector_type(16)));

__device__ __forceinline__ f16x8 zero8() {
  f16x8 v;
#pragma unroll
  for (int j = 0; j < 8; ++j) v[j] = (f16)0.f;
  return v;
}

__device__ __forceinline__ f16x8 cvt8p(const float* p) {
  float4 a = *(const float4*)p;
  float4 b = *(const float4*)(p + 4);
  f16x8 v;
  v[0] = (f16)a.x; v[1] = (f16)a.y; v[2] = (f16)a.z; v[3] = (f16)a.w;
  v[4] = (f16)b.x; v[5] = (f16)b.y; v[6] = (f16)b.z; v[7] = (f16)b.w;
  return v;
}

__device__ __forceinline__ void gload16(const void* g, void* l) {
  __builtin_amdgcn_global_load_lds((const __attribute__((address_space(1))) unsigned int*)g,
                                   (__attribute__((address_space(3))) unsigned int*)l, 16, 0, 0);
}

__device__ __forceinline__ float sigm(float x) {
  return __builtin_amdgcn_rcpf(1.f + __expf(-x));
}
__device__ __forceinline__ float tanh_(float x) {
  x = fminf(15.f, fmaxf(-15.f, x));
  float e = __expf(2.f * x);
  return 1.f - 2.f * __builtin_amdgcn_rcpf(e + 1.f);
}

// ---------------- small utility kernels ----------------

__global__ void k_cvt8(const float* __restrict__ x, f16* __restrict__ y, long n) {
  long i = ((long)blockIdx.x * blockDim.x + threadIdx.x) * 8;
  long stride = (long)gridDim.x * blockDim.x * 8;
  for (; i < n; i += stride) *(f16x8*)(y + i) = cvt8p(x + i);
}

// k_gru weight image: [hb 8][kc 8][R 96][slot 8][8 f16]
// hb = hcol>>5; R = gate*32 + trow (trow = hcol&31). kc 0-3: Wc k=kc*64+kl;
// kc 4-7: Whh k=(kc-4)*64+kl. slot = (kl>>3) ^ (trow&7).
__global__ void k_wc2(const float* __restrict__ Wih, const float* __restrict__ W,
                      unsigned char* __restrict__ dstb) {
  int j = blockIdx.x;   // 0..767 = gate*256 + hcol
  int k = threadIdx.x;  // 0..255
  float s = 0.f;
  for (int c = 0; c < 256; ++c) s = fmaf(Wih[j * 256 + c], W[c * 256 + k], s);
  int g = j >> 8, hcol = j & 255;
  int hb = hcol >> 5, trow = hcol & 31;
  int kc = k >> 6, kl = k & 63;
  int slot = (kl >> 3) ^ (trow & 7);
  size_t byte = (size_t)hb * 98304 + (size_t)kc * 12288 +
                (size_t)(g * 32 + trow) * 128 + slot * 16 + (kl & 7) * 2;
  *(f16*)(dstb + byte) = (f16)s;
}

__global__ void k_whh2(const float* __restrict__ Whh, unsigned char* __restrict__ dstb) {
  int j = blockIdx.x;
  int k = threadIdx.x;
  float s = Whh[j * 256 + k];
  int g = j >> 8, hcol = j & 255;
  int hb = hcol >> 5, trow = hcol & 31;
  int kc = 4 + (k >> 6), kl = k & 63;
  int slot = (kl >> 3) ^ (trow & 7);
  size_t byte = (size_t)hb * 98304 + (size_t)kc * 12288 +
                (size_t)(g * 32 + trow) * 128 + slot * 16 + (kl & 7) * 2;
  *(f16*)(dstb + byte) = (f16)s;
}

// k_fn v2 weight image: [cg 4][kc 8][R 64][slot 8][8 f16]
// out col j: cg = j>>6, R = j&63. k: kc = k>>6, kl = k&63, slot = (kl>>3)^(R&7).
__global__ void k_prepw(const float* __restrict__ w, unsigned char* __restrict__ dstb) {
  int j = blockIdx.x;  // output col 0..255
  int cg = j >> 6, R = j & 63;
  for (int k = threadIdx.x; k < 512; k += 256) {
    int kc = k >> 6, kl = k & 63;
    int slot = (kl >> 3) ^ (R & 7);
    size_t byte = (size_t)(cg * 8 + kc) * 8192 + (size_t)R * 128 + slot * 16 + (kl & 7) * 2;
    *(f16*)(dstb + byte) = (f16)w[j * 512 + k];
  }
}

__global__ void k_v(const float* __restrict__ Wih, const float* __restrict__ b,
                    float* __restrict__ v) {
  int j = blockIdx.x * blockDim.x + threadIdx.x;
  if (j < 768) {
    float s = 0.f;
    for (int c = 0; c < 256; ++c) s = fmaf(Wih[j * 256 + c], b[c], s);
    v[j] = s;
  }
}

__global__ void k_hist(const int* __restrict__ dst, int* __restrict__ cnt, int E) {
  int e = blockIdx.x * 256 + threadIdx.x;
  if (e < E) atomicAdd(&cnt[dst[e]], 1);
}

__global__ void k_scan1(const int* __restrict__ deg, int* __restrict__ rowptr,
                        int* __restrict__ bsum, int n) {
  __shared__ int buf[256];
  int i = blockIdx.x * 256 + threadIdx.x;
  int v = (i < n) ? deg[i] : 0;
  buf[threadIdx.x] = v;
  __syncthreads();
  for (int off = 1; off < 256; off <<= 1) {
    int t = 0;
    if ((int)threadIdx.x >= off) t = buf[threadIdx.x - off];
    __syncthreads();
    buf[threadIdx.x] += t;
    __syncthreads();
  }
  if (i < n) rowptr[i] = buf[threadIdx.x] - v;
  if (threadIdx.x == 255) bsum[blockIdx.x] = buf[255];
}

__global__ void k_scan2(int* __restrict__ bsum, int nb) {
  __shared__ int buf[1024];
  int v = ((int)threadIdx.x < nb) ? bsum[threadIdx.x] : 0;
  buf[threadIdx.x] = v;
  __syncthreads();
  for (int off = 1; off < 1024; off <<= 1) {
    int t = 0;
    if ((int)threadIdx.x >= off) t = buf[threadIdx.x - off];
    __syncthreads();
    buf[threadIdx.x] += t;
    __syncthreads();
  }
  if ((int)threadIdx.x < nb) bsum[threadIdx.x] = buf[threadIdx.x] - v;
}

__global__ void k_scan3(int* __restrict__ rowptr, const int* __restrict__ bsum,
                        int n, int E) {
  int i = blockIdx.x * 256 + threadIdx.x;
  if (i < n) rowptr[i] += bsum[blockIdx.x];
  if (i == n) rowptr[n] = E;
}

__global__ void k_fill(const int* __restrict__ src, const int* __restrict__ dst,
                       const int* __restrict__ rowptr, int* __restrict__ cnt,
                       int* __restrict__ esrc, int E) {
  int e = blockIdx.x * 256 + threadIdx.x;
  if (e < E) {
    int d = dst[e];
    int r = atomicAdd(&cnt[d], 1);
    esrc[rowptr[d] + r] = src[e];
  }
}

// 2-edge unrolled gather: 2 row-loads in flight per iteration
__global__ void k_gather(const f16* __restrict__ h, const int* __restrict__ rowptr,
                         const int* __restrict__ esrc, f16* __restrict__ ag, int n) {
  int g = threadIdx.x >> 5, l = threadIdx.x & 31;
  int node = blockIdx.x * 8 + g;
  if (node >= n) return;
  int e0 = rowptr[node], e1 = rowptr[node + 1];
  float acc[8];
#pragma unroll
  for (int j = 0; j < 8; ++j) acc[j] = 0.f;
  int e = e0;
  for (; e + 2 <= e1; e += 2) {
    int s0 = esrc[e], s1 = esrc[e + 1];
    f16x8 hv0 = *(const f16x8*)(h + (long)s0 * 256 + l * 8);
    f16x8 hv1 = *(const f16x8*)(h + (long)s1 * 256 + l * 8);
#pragma unroll
    for (int j = 0; j < 8; ++j) acc[j] += (float)hv0[j] + (float)hv1[j];
  }
  if (e < e1) {
    int s0 = esrc[e];
    f16x8 hv0 = *(const f16x8*)(h + (long)s0 * 256 + l * 8);
#pragma unroll
    for (int j = 0; j < 8; ++j) acc[j] += (float)hv0[j];
  }
  f16x8 o;
#pragma unroll
  for (int j = 0; j < 8; ++j) o[j] = (f16)acc[j];
  *(f16x8*)(ag + (long)node * 256 + l * 8) = o;
}

// ---------------- fused GRU kernel v9 (unchanged from round 9) ----------------
__global__ __launch_bounds__(256, 4) void k_gru(
    const f16* __restrict__ ag, const f16* __restrict__ hin,
    const unsigned char* __restrict__ wprep, const float* __restrict__ bih,
    const float* __restrict__ bhh, const float* __restrict__ vv,
    const int* __restrict__ rowptr, f16* __restrict__ hout, int n, int nper) {
  __shared__ unsigned char SM[24576 + 512];
  float* Ds = (float*)(SM + 24576);  // deg[128]
  int bid = blockIdx.x;
  int w = (bid & 7) * nper + (bid >> 3);
  int rt = w >> 3, hb = w & 7;
  int row0 = rt * 128;
  int tid = threadIdx.x, lane = tid & 63, wid = tid >> 6;
  int l31 = lane & 31, hi = lane >> 5;
  const unsigned char* wb = wprep + (size_t)hb * 98304;

  auto stage = [&](int c, unsigned char* dst) {
    const unsigned char* s0 = wb + (size_t)c * 12288;
#pragma unroll
    for (int i = 0; i < 3; ++i) {
      int r = i * 4 + wid;
      gload16(s0 + r * 1024 + lane * 16, dst + r * 1024);
    }
  };

  int arow = row0 + wid * 32 + l31;
  bool aok = arow < n;
  const f16* agp = ag + (size_t)arow * 256 + hi * 8;
  const f16* hp = hin + (size_t)arow * 256 + hi * 8;

  f16x8 a[4];
  auto loadA = [&](const f16* p, int koff) {
#pragma unroll
    for (int ks = 0; ks < 4; ++ks)
      a[ks] = aok ? *(const f16x8*)(p + koff + ks * 16) : zero8();
  };
  int sl0 = l31 & 7;
  auto runC = [&](const unsigned char* Bb, f32x16& aR, f32x16& aZ, f32x16& aN) {
#pragma unroll
    for (int ks = 0; ks < 4; ++ks) {
      int sl = (ks * 2 + hi) ^ sl0;
      const unsigned char* base = Bb + sl * 16;
      f16x8 b0 = *(const f16x8*)(base + (0 * 32 + l31) * 128);
      aR = __builtin_amdgcn_mfma_f32_32x32x16_f16(a[ks], b0, aR, 0, 0, 0);
      f16x8 b1 = *(const f16x8*)(base + (1 * 32 + l31) * 128);
      aZ = __builtin_amdgcn_mfma_f32_32x32x16_f16(a[ks], b1, aZ, 0, 0, 0);
      f16x8 b2 = *(const f16x8*)(base + (2 * 32 + l31) * 128);
      aN = __builtin_amdgcn_mfma_f32_32x32x16_f16(a[ks], b2, aN, 0, 0, 0);
    }
  };

  f32x16 accR, accZ, accNI, accNH;
#pragma unroll
  for (int j = 0; j < 16; ++j) { accR[j] = 0.f; accZ[j] = 0.f; accNI[j] = 0.f; accNH[j] = 0.f; }

  stage(0, SM);
  loadA(agp, 0);
  if (tid < 128) {
    int grow = row0 + tid;
    Ds[tid] = (grow < n) ? (float)(rowptr[grow + 1] - rowptr[grow]) : 0.f;
  }
  __syncthreads();

  stage(1, SM + 12288);
  runC(SM, accR, accZ, accNI);
  loadA(agp, 64);
  __syncthreads();
  stage(2, SM);
  runC(SM + 12288, accR, accZ, accNI);
  loadA(agp, 128);
  __syncthreads();
  stage(3, SM + 12288);
  runC(SM, accR, accZ, accNI);
  loadA(agp, 192);
  __syncthreads();
  stage(4, SM);
  runC(SM + 12288, accR, accZ, accNI);
  loadA(hp, 0);
  __syncthreads();
  stage(5, SM + 12288);
  runC(SM, accR, accZ, accNH);
  loadA(hp, 64);
  __syncthreads();
  stage(6, SM);
  runC(SM + 12288, accR, accZ, accNH);
  loadA(hp, 128);
  __syncthreads();
  stage(7, SM + 12288);
  runC(SM, accR, accZ, accNH);
  loadA(hp, 192);
  __syncthreads();
  runC(SM + 12288, accR, accZ, accNH);

  int gcol = hb * 32 + l31;
  float br = bih[gcol] + bhh[gcol];
  float bz = bih[256 + gcol] + bhh[256 + gcol];
  float bi_n = bih[512 + gcol], bh_n = bhh[512 + gcol];
  float vr = vv[gcol], vz = vv[256 + gcol], vn = vv[512 + gcol];
  int wrow = wid * 32;

#pragma unroll
  for (int rg = 0; rg < 16; ++rg) {
    int crow = (rg & 3) + 8 * (rg >> 2) + 4 * hi;
    int grow = row0 + wrow + crow;
    float dg = Ds[wrow + crow];
    float hold = (grow < n) ? (float)hin[(size_t)grow * 256 + gcol] : 0.f;
    float r = sigm(accR[rg] + br + dg * vr);
    float z = sigm(accZ[rg] + bz + dg * vz);
    float nn = tanh_(accNI[rg] + bi_n + dg * vn + r * (accNH[rg] + bh_n));
    if (grow < n)
      hout[(size_t)grow * 256 + gcol] = (f16)((1.f - z) * nn + z * hold);
  }
}

// ---------------- fused concat-linear v2: out = [hb16 | base16] @ w^T + bias ----
// k_gru-style: 256 thr / 4 waves, block = 128 rows x 64 cols (cg), 8 K-chunks of
// 8KB double-buffered, acc = 2 tiles (32 AGPR) -> high occupancy. All-f16 A.
__global__ __launch_bounds__(256, 4) void k_fn(
    const f16* __restrict__ hb, const f16* __restrict__ base16,
    const unsigned char* __restrict__ wp, const float* __restrict__ bias,
    float* __restrict__ out, int n, int nper) {
  __shared__ unsigned char SM[16384];
  int bid = blockIdx.x;
  int w = (bid & 7) * nper + (bid >> 3);  // XCD swizzle (nwg % 8 == 0)
  int rt = w >> 2, cg = w & 3;
  int row0 = rt * 128;
  int tid = threadIdx.x, lane = tid & 63, wid = tid >> 6;
  int l31 = lane & 31, hi = lane >> 5;
  const unsigned char* wb = wp + (size_t)cg * 65536;

  auto stage = [&](int c, unsigned char* dst) {
    const unsigned char* s0 = wb + (size_t)c * 8192;
#pragma unroll
    for (int i = 0; i < 2; ++i) {
      int r = i * 4 + wid;
      gload16(s0 + r * 1024 + lane * 16, dst + r * 1024);
    }
  };

  int arow = row0 + wid * 32 + l31;
  bool aok = arow < n;
  const f16* hbp = hb + (size_t)arow * 256 + hi * 8;
  const f16* bsp = base16 + (size_t)arow * 256 + hi * 8;

  f16x8 a[4];
  auto loadA = [&](const f16* p, int koff) {
#pragma unroll
    for (int ks = 0; ks < 4; ++ks)
      a[ks] = aok ? *(const f16x8*)(p + koff + ks * 16) : zero8();
  };
  int sl0 = l31 & 7;

  f32x16 acc0, acc1;
#pragma unroll
  for (int j = 0; j < 16; ++j) { acc0[j] = 0.f; acc1[j] = 0.f; }

  auto runC = [&](const unsigned char* Bb) {
#pragma unroll
    for (int ks = 0; ks < 4; ++ks) {
      int sl = (ks * 2 + hi) ^ sl0;
      const unsigned char* base = Bb + sl * 16;
      f16x8 b0 = *(const f16x8*)(base + (0 + l31) * 128);
      acc0 = __builtin_amdgcn_mfma_f32_32x32x16_f16(a[ks], b0, acc0, 0, 0, 0);
      f16x8 b1 = *(const f16x8*)(base + (32 + l31) * 128);
      acc1 = __builtin_amdgcn_mfma_f32_32x32x16_f16(a[ks], b1, acc1, 0, 0, 0);
    }
  };

  stage(0, SM);
  loadA(hbp, 0);
  __syncthreads();
  stage(1, SM + 8192); runC(SM);        loadA(hbp, 64);  __syncthreads();
  stage(2, SM);        runC(SM + 8192); loadA(hbp, 128); __syncthreads();
  stage(3, SM + 8192); runC(SM);        loadA(hbp, 192); __syncthreads();
  stage(4, SM);        runC(SM + 8192); loadA(bsp, 0);   __syncthreads();
  stage(5, SM + 8192); runC(SM);        loadA(bsp, 64);  __syncthreads();
  stage(6, SM);        runC(SM + 8192); loadA(bsp, 128); __syncthreads();
  stage(7, SM + 8192); runC(SM);        loadA(bsp, 192); __syncthreads();
  runC(SM + 8192);

  int colb = cg * 64;
  float bb0 = bias[colb + l31], bb1 = bias[colb + 32 + l31];
#pragma unroll
  for (int rg = 0; rg < 16; ++rg) {
    int grow = row0 + wid * 32 + (rg & 3) + 8 * (rg >> 2) + 4 * hi;
    if (grow < n) {
      out[(size_t)grow * 256 + colb + l31] = acc0[rg] + bb0;
      out[(size_t)grow * 256 + colb + 32 + l31] = acc1[rg] + bb1;
    }
  }
}

// ---------------- launch ----------------
extern "C" void kernel_launch(void* const* d_in, const int* in_sizes, int n_in,
                              void* d_out, int out_size, void* d_ws, size_t ws_size,
                              hipStream_t stream) {
  const float* nodes = (const float*)d_in[0];
  const int* asrc = (const int*)d_in[1];
  const int* adst = (const int*)d_in[2];
  const int* csrc = (const int*)d_in[3];
  const int* cdst = (const int*)d_in[4];
  const float* W_ast = (const float*)d_in[5];
  const float* b_ast = (const float*)d_in[6];
  const float* Wih_a = (const float*)d_in[7];
  const float* Whh_a = (const float*)d_in[8];
  const float* bih_a = (const float*)d_in[9];
  const float* bhh_a = (const float*)d_in[10];
  const float* w1 = (const float*)d_in[11];
  const float* b1 = (const float*)d_in[12];
  const float* W_cpg = (const float*)d_in[13];
  const float* b_cpg = (const float*)d_in[14];
  const float* Wih_c = (const float*)d_in[15];
  const float* Whh_c = (const float*)d_in[16];
  const float* bih_c = (const float*)d_in[17];
  const float* bhh_c = (const float*)d_in[18];
  const float* w2 = (const float*)d_in[19];
  const float* b2 = (const float*)d_in[20];
  float* out = (float*)d_out;

  const int N = in_sizes[0] / 256;  // 150000
  const int EA = in_sizes[1];       // 300000
  const int EC = in_sizes[3];       // 250000
  const long ND = (long)N * 256;

  char* ws = (char*)d_ws;
  size_t off = 0;
  auto carve = [&](size_t bytes) -> char* {
    char* p = ws + off;
    off += (bytes + 255) & ~(size_t)255;
    return p;
  };
  f16* h0 = (f16*)carve(ND * 2);
  f16* h1 = (f16*)carve(ND * 2);
  f16* ag = (f16*)carve(ND * 2);
  f16* nd16 = (f16*)carve(ND * 2);  // f16 nodes -> later recycled as f16 hiddens
  unsigned char* wpA = (unsigned char*)carve(786432);  // 8 hb x 8 kc x 12288B
  unsigned char* wpC = (unsigned char*)carve(786432);
  unsigned char* w1p = (unsigned char*)carve(262144);  // 4 cg x 8 kc x 8192B
  unsigned char* w2p = (unsigned char*)carve(262144);
  float* vA = (float*)carve(768 * 4);
  float* vC = (float*)carve(768 * 4);
  int* rowptr = (int*)carve((size_t)(N + 1) * 4);
  int* cnt = (int*)carve((size_t)N * 4);
  int* esrc = (int*)carve((size_t)(EA > EC ? EA : EC) * 4);
  int* bsum = (int*)carve(1024 * 4);
  (void)ws_size; (void)n_in; (void)out_size;

  const int NRB = (N + 127) / 128;   // 1172 row-panels
  const int GGRID = NRB * 8;         // k_gru grid (9376, %8==0)
  const int FGRID = NRB * 4;         // k_fn grid (4688, %8==0)
  const int SBLK = (N + 255) / 256;  // 586 for scans
  auto cvt = [&](const float* x, f16* y, long n) {
    int blocks = (int)((n / 8 + 255) / 256);
    if (blocks > 2048) blocks = 2048;
    k_cvt8<<<blocks, 256, 0, stream>>>(x, y, n);
  };

  // weight prep
  k_wc2<<<768, 256, 0, stream>>>(Wih_a, W_ast, wpA);
  k_wc2<<<768, 256, 0, stream>>>(Wih_c, W_cpg, wpC);
  k_whh2<<<768, 256, 0, stream>>>(Whh_a, wpA);
  k_whh2<<<768, 256, 0, stream>>>(Whh_c, wpC);
  k_prepw<<<256, 256, 0, stream>>>(w1, w1p);
  k_prepw<<<256, 256, 0, stream>>>(w2, w2p);
  k_v<<<3, 256, 0, stream>>>(Wih_a, b_ast, vA);
  k_v<<<3, 256, 0, stream>>>(Wih_c, b_cpg, vC);
  cvt(nodes, nd16, ND);

  auto run_branch = [&](const int* src, const int* dst, int E, const unsigned char* wprep,
                        const float* bih, const float* bhh, const float* v,
                        const f16* hstart) {
    hipMemsetAsync(cnt, 0, (size_t)N * 4, stream);
    k_hist<<<(E + 255) / 256, 256, 0, stream>>>(dst, cnt, E);
    k_scan1<<<SBLK, 256, 0, stream>>>(cnt, rowptr, bsum, N);
    k_scan2<<<1, 1024, 0, stream>>>(bsum, SBLK);
    k_scan3<<<SBLK, 256, 0, stream>>>(rowptr, bsum, N, E);
    hipMemsetAsync(cnt, 0, (size_t)N * 4, stream);
    k_fill<<<(E + 255) / 256, 256, 0, stream>>>(src, dst, rowptr, cnt, esrc, E);
    k_gather<<<(N + 7) / 8, 256, 0, stream>>>(hstart, rowptr, esrc, ag, N);
    k_gru<<<GGRID, 256, 0, stream>>>(ag, hstart, wprep, bih, bhh, v, rowptr, h1, N, NRB);
    k_gather<<<(N + 7) / 8, 256, 0, stream>>>(h1, rowptr, esrc, ag, N);
    k_gru<<<GGRID, 256, 0, stream>>>(ag, h1, wprep, bih, bhh, v, rowptr, h0, N, NRB);
  };

  // AST branch from f16(nodes); ends with h_ast in h0
  run_branch(asrc, adst, EA, wpA, bih_a, bhh_a, vA, nd16);
  // hiddens = [h_ast | nodes] @ w1^T + b1 -> out (fp32); bases all f16
  k_fn<<<FGRID, 256, 0, stream>>>(h0, nd16, w1p, b1, out, N, NRB * 4 / 8);
  // recycle nd16 as f16 hiddens
  cvt(out, nd16, ND);
  // CPG branch from f16(hiddens); ends with h_cpg in h0
  run_branch(csrc, cdst, EC, wpC, bih_c, bhh_c, vC, nd16);
  // logits = [h_cpg | hiddens] @ w2^T + b2 -> out (no aliasing: base is nd16)
  k_fn<<<FGRID, 256, 0, stream>>>(h0, nd16, w2p, b2, out, N, NRB * 4 / 8);
}

// Round 13
// 1311.275 us; speedup vs baseline: 1.5170x; 1.0557x over previous
//
#include <hip/hip_runtime.h>

typedef _Float16 f16;
typedef _Float16 f16x8 __attribute__((ext_vector_type(8)));
typedef float f32x16 __attribute__((ext_vector_type(16)));

__device__ __forceinline__ f16x8 cvt8p(const float* p) {
  float4 a = *(const float4*)p;
  float4 b = *(const float4*)(p + 4);
  f16x8 v;
  v[0] = (f16)a.x; v[1] = (f16)a.y; v[2] = (f16)a.z; v[3] = (f16)a.w;
  v[4] = (f16)b.x; v[5] = (f16)b.y; v[6] = (f16)b.z; v[7] = (f16)b.w;
  return v;
}

__device__ __forceinline__ void gload16(const void* g, void* l) {
  __builtin_amdgcn_global_load_lds((const __attribute__((address_space(1))) unsigned int*)g,
                                   (__attribute__((address_space(3))) unsigned int*)l, 16, 0, 0);
}

__device__ __forceinline__ float sigm(float x) {
  return __builtin_amdgcn_rcpf(1.f + __expf(-x));
}
__device__ __forceinline__ float tanh_(float x) {
  x = fminf(15.f, fmaxf(-15.f, x));
  float e = __expf(2.f * x);
  return 1.f - 2.f * __builtin_amdgcn_rcpf(e + 1.f);
}

// ---------------- small utility kernels ----------------

__global__ void k_cvt8(const float* __restrict__ x, f16* __restrict__ y, long n) {
  long i = ((long)blockIdx.x * blockDim.x + threadIdx.x) * 8;
  long stride = (long)gridDim.x * blockDim.x * 8;
  for (; i < n; i += stride) *(f16x8*)(y + i) = cvt8p(x + i);
}

// k_gru weight image: [hb 8][kc 8][R 96][slot 8][8 f16]
// hb = hcol>>5; R = gate*32 + trow (trow = hcol&31). kc 0-3: Wc k=kc*64+kl;
// kc 4-7: Whh k=(kc-4)*64+kl. slot = (kl>>3) ^ (trow&7).
__global__ void k_wc2(const float* __restrict__ Wih, const float* __restrict__ W,
                      unsigned char* __restrict__ dstb) {
  int j = blockIdx.x;   // 0..767 = gate*256 + hcol
  int k = threadIdx.x;  // 0..255
  float s = 0.f;
  for (int c = 0; c < 256; ++c) s = fmaf(Wih[j * 256 + c], W[c * 256 + k], s);
  int g = j >> 8, hcol = j & 255;
  int hb = hcol >> 5, trow = hcol & 31;
  int kc = k >> 6, kl = k & 63;
  int slot = (kl >> 3) ^ (trow & 7);
  size_t byte = (size_t)hb * 98304 + (size_t)kc * 12288 +
                (size_t)(g * 32 + trow) * 128 + slot * 16 + (kl & 7) * 2;
  *(f16*)(dstb + byte) = (f16)s;
}

__global__ void k_whh2(const float* __restrict__ Whh, unsigned char* __restrict__ dstb) {
  int j = blockIdx.x;
  int k = threadIdx.x;
  float s = Whh[j * 256 + k];
  int g = j >> 8, hcol = j & 255;
  int hb = hcol >> 5, trow = hcol & 31;
  int kc = 4 + (k >> 6), kl = k & 63;
  int slot = (kl >> 3) ^ (trow & 7);
  size_t byte = (size_t)hb * 98304 + (size_t)kc * 12288 +
                (size_t)(g * 32 + trow) * 128 + slot * 16 + (kl & 7) * 2;
  *(f16*)(dstb + byte) = (f16)s;
}

// k_fn weight image: [cg 4][kc 8][R 64][slot 8][8 f16]
__global__ void k_prepw(const float* __restrict__ w, unsigned char* __restrict__ dstb) {
  int j = blockIdx.x;  // output col 0..255
  int cg = j >> 6, R = j & 63;
  for (int k = threadIdx.x; k < 512; k += 256) {
    int kc = k >> 6, kl = k & 63;
    int slot = (kl >> 3) ^ (R & 7);
    size_t byte = (size_t)(cg * 8 + kc) * 8192 + (size_t)R * 128 + slot * 16 + (kl & 7) * 2;
    *(f16*)(dstb + byte) = (f16)w[j * 512 + k];
  }
}

__global__ void k_v(const float* __restrict__ Wih, const float* __restrict__ b,
                    float* __restrict__ v) {
  int j = blockIdx.x * blockDim.x + threadIdx.x;
  if (j < 768) {
    float s = 0.f;
    for (int c = 0; c < 256; ++c) s = fmaf(Wih[j * 256 + c], b[c], s);
    v[j] = s;
  }
}

__global__ void k_hist(const int* __restrict__ dst, int* __restrict__ cnt, int E) {
  int e = blockIdx.x * 256 + threadIdx.x;
  if (e < E) atomicAdd(&cnt[dst[e]], 1);
}

__global__ void k_scan1(const int* __restrict__ deg, int* __restrict__ rowptr,
                        int* __restrict__ bsum, int n) {
  __shared__ int buf[256];
  int i = blockIdx.x * 256 + threadIdx.x;
  int v = (i < n) ? deg[i] : 0;
  buf[threadIdx.x] = v;
  __syncthreads();
  for (int off = 1; off < 256; off <<= 1) {
    int t = 0;
    if ((int)threadIdx.x >= off) t = buf[threadIdx.x - off];
    __syncthreads();
    buf[threadIdx.x] += t;
    __syncthreads();
  }
  if (i < n) rowptr[i] = buf[threadIdx.x] - v;
  if (threadIdx.x == 255) bsum[blockIdx.x] = buf[255];
}

__global__ void k_scan2(int* __restrict__ bsum, int nb) {
  __shared__ int buf[1024];
  int v = ((int)threadIdx.x < nb) ? bsum[threadIdx.x] : 0;
  buf[threadIdx.x] = v;
  __syncthreads();
  for (int off = 1; off < 1024; off <<= 1) {
    int t = 0;
    if ((int)threadIdx.x >= off) t = buf[threadIdx.x - off];
    __syncthreads();
    buf[threadIdx.x] += t;
    __syncthreads();
  }
  if ((int)threadIdx.x < nb) bsum[threadIdx.x] = buf[threadIdx.x] - v;
}

__global__ void k_scan3(int* __restrict__ rowptr, const int* __restrict__ bsum,
                        int n, int E) {
  int i = blockIdx.x * 256 + threadIdx.x;
  if (i < n) rowptr[i] += bsum[blockIdx.x];
  if (i == n) rowptr[n] = E;
}

__global__ void k_fill(const int* __restrict__ src, const int* __restrict__ dst,
                       const int* __restrict__ rowptr, int* __restrict__ cnt,
                       int* __restrict__ esrc, int E) {
  int e = blockIdx.x * 256 + threadIdx.x;
  if (e < E) {
    int d = dst[e];
    int r = atomicAdd(&cnt[d], 1);
    esrc[rowptr[d] + r] = src[e];
  }
}

// 2-edge unrolled gather
__global__ void k_gather(const f16* __restrict__ h, const int* __restrict__ rowptr,
                         const int* __restrict__ esrc, f16* __restrict__ ag, int n) {
  int g = threadIdx.x >> 5, l = threadIdx.x & 31;
  int node = blockIdx.x * 8 + g;
  if (node >= n) return;
  int e0 = rowptr[node], e1 = rowptr[node + 1];
  float acc[8];
#pragma unroll
  for (int j = 0; j < 8; ++j) acc[j] = 0.f;
  int e = e0;
  for (; e + 2 <= e1; e += 2) {
    int s0 = esrc[e], s1 = esrc[e + 1];
    f16x8 hv0 = *(const f16x8*)(h + (long)s0 * 256 + l * 8);
    f16x8 hv1 = *(const f16x8*)(h + (long)s1 * 256 + l * 8);
#pragma unroll
    for (int j = 0; j < 8; ++j) acc[j] += (float)hv0[j] + (float)hv1[j];
  }
  if (e < e1) {
    int s0 = esrc[e];
    f16x8 hv0 = *(const f16x8*)(h + (long)s0 * 256 + l * 8);
#pragma unroll
    for (int j = 0; j < 8; ++j) acc[j] += (float)hv0[j];
  }
  f16x8 o;
#pragma unroll
  for (int j = 0; j < 8; ++j) o[j] = (f16)acc[j];
  *(f16x8*)(ag + (long)node * 256 + l * 8) = o;
}

// ---------------- fused GRU kernel (round-9 structure; unguarded loads) --------
// Note: OOB-row LOADS are intentionally unguarded — they read into the next
// workspace carve (legal); garbage pollutes only discarded rows (stores guarded).
__global__ __launch_bounds__(256, 4) void k_gru(
    const f16* __restrict__ ag, const f16* __restrict__ hin,
    const unsigned char* __restrict__ wprep, const float* __restrict__ bih,
    const float* __restrict__ bhh, const float* __restrict__ vv,
    const int* __restrict__ rowptr, f16* __restrict__ hout, int n, int nper) {
  __shared__ unsigned char SM[24576 + 512];
  float* Ds = (float*)(SM + 24576);  // deg[128]
  int bid = blockIdx.x;
  int w = (bid & 7) * nper + (bid >> 3);
  int rt = w >> 3, hb = w & 7;
  int row0 = rt * 128;
  int tid = threadIdx.x, lane = tid & 63, wid = tid >> 6;
  int l31 = lane & 31, hi = lane >> 5;
  const unsigned char* wb = wprep + (size_t)hb * 98304;

  auto stage = [&](int c, unsigned char* dst) {
    const unsigned char* s0 = wb + (size_t)c * 12288;
#pragma unroll
    for (int i = 0; i < 3; ++i) {
      int r = i * 4 + wid;
      gload16(s0 + r * 1024 + lane * 16, dst + r * 1024);
    }
  };

  int arow = row0 + wid * 32 + l31;
  const f16* agp = ag + (size_t)arow * 256 + hi * 8;
  const f16* hp = hin + (size_t)arow * 256 + hi * 8;

  f16x8 a[4];
  auto loadA = [&](const f16* p, int koff) {
#pragma unroll
    for (int ks = 0; ks < 4; ++ks)
      a[ks] = *(const f16x8*)(p + koff + ks * 16);
  };
  int sl0 = l31 & 7;
  auto runC = [&](const unsigned char* Bb, f32x16& aR, f32x16& aZ, f32x16& aN) {
#pragma unroll
    for (int ks = 0; ks < 4; ++ks) {
      int sl = (ks * 2 + hi) ^ sl0;
      const unsigned char* base = Bb + sl * 16;
      f16x8 b0 = *(const f16x8*)(base + (0 * 32 + l31) * 128);
      aR = __builtin_amdgcn_mfma_f32_32x32x16_f16(a[ks], b0, aR, 0, 0, 0);
      f16x8 b1 = *(const f16x8*)(base + (1 * 32 + l31) * 128);
      aZ = __builtin_amdgcn_mfma_f32_32x32x16_f16(a[ks], b1, aZ, 0, 0, 0);
      f16x8 b2 = *(const f16x8*)(base + (2 * 32 + l31) * 128);
      aN = __builtin_amdgcn_mfma_f32_32x32x16_f16(a[ks], b2, aN, 0, 0, 0);
    }
  };

  f32x16 accR, accZ, accNI, accNH;
#pragma unroll
  for (int j = 0; j < 16; ++j) { accR[j] = 0.f; accZ[j] = 0.f; accNI[j] = 0.f; accNH[j] = 0.f; }

  stage(0, SM);
  loadA(agp, 0);
  if (tid < 128) {
    int grow = row0 + tid;
    Ds[tid] = (grow < n) ? (float)(rowptr[grow + 1] - rowptr[grow]) : 0.f;
  }
  __syncthreads();

  stage(1, SM + 12288);
  runC(SM, accR, accZ, accNI);
  loadA(agp, 64);
  __syncthreads();
  stage(2, SM);
  runC(SM + 12288, accR, accZ, accNI);
  loadA(agp, 128);
  __syncthreads();
  stage(3, SM + 12288);
  runC(SM, accR, accZ, accNI);
  loadA(agp, 192);
  __syncthreads();
  stage(4, SM);
  runC(SM + 12288, accR, accZ, accNI);
  loadA(hp, 0);
  __syncthreads();
  stage(5, SM + 12288);
  runC(SM, accR, accZ, accNH);
  loadA(hp, 64);
  __syncthreads();
  stage(6, SM);
  runC(SM + 12288, accR, accZ, accNH);
  loadA(hp, 128);
  __syncthreads();
  stage(7, SM + 12288);
  runC(SM, accR, accZ, accNH);
  loadA(hp, 192);
  __syncthreads();
  runC(SM + 12288, accR, accZ, accNH);

  int gcol = hb * 32 + l31;
  float br = bih[gcol] + bhh[gcol];
  float bz = bih[256 + gcol] + bhh[256 + gcol];
  float bi_n = bih[512 + gcol], bh_n = bhh[512 + gcol];
  float vr = vv[gcol], vz = vv[256 + gcol], vn = vv[512 + gcol];
  int wrow = wid * 32;

#pragma unroll
  for (int rg = 0; rg < 16; ++rg) {
    int crow = (rg & 3) + 8 * (rg >> 2) + 4 * hi;
    int grow = row0 + wrow + crow;
    float dg = Ds[wrow + crow];
    float hold = (float)hin[(size_t)grow * 256 + gcol];
    float r = sigm(accR[rg] + br + dg * vr);
    float z = sigm(accZ[rg] + bz + dg * vz);
    float nn = tanh_(accNI[rg] + bi_n + dg * vn + r * (accNH[rg] + bh_n));
    if (grow < n)
      hout[(size_t)grow * 256 + gcol] = (f16)((1.f - z) * nn + z * hold);
  }
}

// ---------------- fused concat-linear: res = [hb16 | base16] @ w^T + bias ------
// WMODE 0: write fp32 to out32. WMODE 1: write f16 to out16 (skip fp32 entirely).
template <int WMODE>
__global__ __launch_bounds__(256, 4) void k_fn(
    const f16* __restrict__ hb, const f16* __restrict__ base16,
    const unsigned char* __restrict__ wp, const float* __restrict__ bias,
    float* __restrict__ out32, f16* __restrict__ out16, int n, int nper) {
  __shared__ unsigned char SM[16384];
  int bid = blockIdx.x;
  int w = (bid & 7) * nper + (bid >> 3);  // XCD swizzle (nwg % 8 == 0)
  int rt = w >> 2, cg = w & 3;
  int row0 = rt * 128;
  int tid = threadIdx.x, lane = tid & 63, wid = tid >> 6;
  int l31 = lane & 31, hi = lane >> 5;
  const unsigned char* wb = wp + (size_t)cg * 65536;

  auto stage = [&](int c, unsigned char* dst) {
    const unsigned char* s0 = wb + (size_t)c * 8192;
#pragma unroll
    for (int i = 0; i < 2; ++i) {
      int r = i * 4 + wid;
      gload16(s0 + r * 1024 + lane * 16, dst + r * 1024);
    }
  };

  int arow = row0 + wid * 32 + l31;
  const f16* hbp = hb + (size_t)arow * 256 + hi * 8;
  const f16* bsp = base16 + (size_t)arow * 256 + hi * 8;

  f16x8 a[4];
  auto loadA = [&](const f16* p, int koff) {
#pragma unroll
    for (int ks = 0; ks < 4; ++ks)
      a[ks] = *(const f16x8*)(p + koff + ks * 16);
  };
  int sl0 = l31 & 7;

  f32x16 acc0, acc1;
#pragma unroll
  for (int j = 0; j < 16; ++j) { acc0[j] = 0.f; acc1[j] = 0.f; }

  auto runC = [&](const unsigned char* Bb) {
#pragma unroll
    for (int ks = 0; ks < 4; ++ks) {
      int sl = (ks * 2 + hi) ^ sl0;
      const unsigned char* base = Bb + sl * 16;
      f16x8 b0 = *(const f16x8*)(base + (0 + l31) * 128);
      acc0 = __builtin_amdgcn_mfma_f32_32x32x16_f16(a[ks], b0, acc0, 0, 0, 0);
      f16x8 b1 = *(const f16x8*)(base + (32 + l31) * 128);
      acc1 = __builtin_amdgcn_mfma_f32_32x32x16_f16(a[ks], b1, acc1, 0, 0, 0);
    }
  };

  stage(0, SM);
  loadA(hbp, 0);
  __syncthreads();
  stage(1, SM + 8192); runC(SM);        loadA(hbp, 64);  __syncthreads();
  stage(2, SM);        runC(SM + 8192); loadA(hbp, 128); __syncthreads();
  stage(3, SM + 8192); runC(SM);        loadA(hbp, 192); __syncthreads();
  stage(4, SM);        runC(SM + 8192); loadA(bsp, 0);   __syncthreads();
  stage(5, SM + 8192); runC(SM);        loadA(bsp, 64);  __syncthreads();
  stage(6, SM);        runC(SM + 8192); loadA(bsp, 128); __syncthreads();
  stage(7, SM + 8192); runC(SM);        loadA(bsp, 192); __syncthreads();
  runC(SM + 8192);

  int colb = cg * 64;
  float bb0 = bias[colb + l31], bb1 = bias[colb + 32 + l31];
#pragma unroll
  for (int rg = 0; rg < 16; ++rg) {
    int grow = row0 + wid * 32 + (rg & 3) + 8 * (rg >> 2) + 4 * hi;
    if (grow < n) {
      if (WMODE == 0) {
        out32[(size_t)grow * 256 + colb + l31] = acc0[rg] + bb0;
        out32[(size_t)grow * 256 + colb + 32 + l31] = acc1[rg] + bb1;
      } else {
        out16[(size_t)grow * 256 + colb + l31] = (f16)(acc0[rg] + bb0);
        out16[(size_t)grow * 256 + colb + 32 + l31] = (f16)(acc1[rg] + bb1);
      }
    }
  }
}

// ---------------- launch ----------------
extern "C" void kernel_launch(void* const* d_in, const int* in_sizes, int n_in,
                              void* d_out, int out_size, void* d_ws, size_t ws_size,
                              hipStream_t stream) {
  const float* nodes = (const float*)d_in[0];
  const int* asrc = (const int*)d_in[1];
  const int* adst = (const int*)d_in[2];
  const int* csrc = (const int*)d_in[3];
  const int* cdst = (const int*)d_in[4];
  const float* W_ast = (const float*)d_in[5];
  const float* b_ast = (const float*)d_in[6];
  const float* Wih_a = (const float*)d_in[7];
  const float* Whh_a = (const float*)d_in[8];
  const float* bih_a = (const float*)d_in[9];
  const float* bhh_a = (const float*)d_in[10];
  const float* w1 = (const float*)d_in[11];
  const float* b1 = (const float*)d_in[12];
  const float* W_cpg = (const float*)d_in[13];
  const float* b_cpg = (const float*)d_in[14];
  const float* Wih_c = (const float*)d_in[15];
  const float* Whh_c = (const float*)d_in[16];
  const float* bih_c = (const float*)d_in[17];
  const float* bhh_c = (const float*)d_in[18];
  const float* w2 = (const float*)d_in[19];
  const float* b2 = (const float*)d_in[20];
  float* out = (float*)d_out;

  const int N = in_sizes[0] / 256;  // 150000
  const int EA = in_sizes[1];       // 300000
  const int EC = in_sizes[3];       // 250000
  const long ND = (long)N * 256;

  char* ws = (char*)d_ws;
  size_t off = 0;
  auto carve = [&](size_t bytes) -> char* {
    char* p = ws + off;
    off += (bytes + 255) & ~(size_t)255;
    return p;
  };
  f16* h0 = (f16*)carve(ND * 2);
  f16* h1 = (f16*)carve(ND * 2);
  f16* ag = (f16*)carve(ND * 2);
  f16* nd16 = (f16*)carve(ND * 2);
  unsigned char* wpA = (unsigned char*)carve(786432);  // 8 hb x 8 kc x 12288B
  unsigned char* wpC = (unsigned char*)carve(786432);
  unsigned char* w1p = (unsigned char*)carve(262144);  // 4 cg x 8 kc x 8192B
  unsigned char* w2p = (unsigned char*)carve(262144);
  float* vA = (float*)carve(768 * 4);
  float* vC = (float*)carve(768 * 4);
  int* rowptr = (int*)carve((size_t)(N + 1) * 4);
  int* cnt = (int*)carve((size_t)N * 4);
  int* esrc = (int*)carve((size_t)(EA > EC ? EA : EC) * 4);
  int* bsum = (int*)carve(1024 * 4);
  (void)ws_size; (void)n_in; (void)out_size;

  const int NRB = (N + 127) / 128;   // 1172 row-panels
  const int GGRID = NRB * 8;         // k_gru grid (%8==0)
  const int FGRID = NRB * 4;         // k_fn grid (%8==0)
  const int SBLK = (N + 255) / 256;  // scans
  {
    int blocks = (int)((ND / 8 + 255) / 256);
    if (blocks > 2048) blocks = 2048;
    k_cvt8<<<blocks, 256, 0, stream>>>(nodes, nd16, ND);
  }

  // weight prep
  k_wc2<<<768, 256, 0, stream>>>(Wih_a, W_ast, wpA);
  k_wc2<<<768, 256, 0, stream>>>(Wih_c, W_cpg, wpC);
  k_whh2<<<768, 256, 0, stream>>>(Whh_a, wpA);
  k_whh2<<<768, 256, 0, stream>>>(Whh_c, wpC);
  k_prepw<<<256, 256, 0, stream>>>(w1, w1p);
  k_prepw<<<256, 256, 0, stream>>>(w2, w2p);
  k_v<<<3, 256, 0, stream>>>(Wih_a, b_ast, vA);
  k_v<<<3, 256, 0, stream>>>(Wih_c, b_cpg, vC);

  // run_branch: hstart -> t1 -> t2 (t1,t2 distinct from hstart and ag)
  auto run_branch = [&](const int* src, const int* dst, int E, const unsigned char* wprep,
                        const float* bih, const float* bhh, const float* v,
                        const f16* hstart, f16* t1, f16* t2) {
    hipMemsetAsync(cnt, 0, (size_t)N * 4, stream);
    k_hist<<<(E + 255) / 256, 256, 0, stream>>>(dst, cnt, E);
    k_scan1<<<SBLK, 256, 0, stream>>>(cnt, rowptr, bsum, N);
    k_scan2<<<1, 1024, 0, stream>>>(bsum, SBLK);
    k_scan3<<<SBLK, 256, 0, stream>>>(rowptr, bsum, N, E);
    hipMemsetAsync(cnt, 0, (size_t)N * 4, stream);
    k_fill<<<(E + 255) / 256, 256, 0, stream>>>(src, dst, rowptr, cnt, esrc, E);
    k_gather<<<(N + 7) / 8, 256, 0, stream>>>(hstart, rowptr, esrc, ag, N);
    k_gru<<<GGRID, 256, 0, stream>>>(ag, hstart, wprep, bih, bhh, v, rowptr, t1, N, NRB);
    k_gather<<<(N + 7) / 8, 256, 0, stream>>>(t1, rowptr, esrc, ag, N);
    k_gru<<<GGRID, 256, 0, stream>>>(ag, t1, wprep, bih, bhh, v, rowptr, t2, N, NRB);
  };

  // AST branch: nd16 -> h1 -> h0 (h_ast in h0; nd16 = nodes still alive)
  run_branch(asrc, adst, EA, wpA, bih_a, bhh_a, vA, nd16, h1, h0);
  // hiddens (f16) = [h_ast | nodes] @ w1^T + b1 -> h1 (no fp32 write, no cvt)
  k_fn<1><<<FGRID, 256, 0, stream>>>(h0, nd16, w1p, b1, nullptr, h1, N, FGRID / 8);
  // CPG branch: h1 -> h0 -> nd16 (h_cpg in nd16; h1 = hiddens stays alive)
  run_branch(csrc, cdst, EC, wpC, bih_c, bhh_c, vC, h1, h0, nd16);
  // logits (fp32) = [h_cpg | hiddens] @ w2^T + b2 -> d_out
  k_fn<0><<<FGRID, 256, 0, stream>>>(nd16, h1, w2p, b2, out, nullptr, N, FGRID / 8);
}